// Round 9
// baseline (785.558 us; speedup 1.0000x reference)
//
#include <hip/hip_runtime.h>
#include <stdint.h>

#define IN_C 128
#define HC 256

// ---- xw = x @ W, fp32, one block per node ----
__global__ __launch_bounds__(256) void k_gemm(const float* __restrict__ x,
                                              const float* __restrict__ W,
                                              float* __restrict__ xw) {
    __shared__ float sx[IN_C];
    int node = blockIdx.x;
    int c = threadIdx.x;
    if (c < IN_C) sx[c] = x[(size_t)node * IN_C + c];
    __syncthreads();
    float acc = 0.f;
    for (int k = 0; k < IN_C; ++k) acc = fmaf(sx[k], W[k * HC + c], acc);
    xw[(size_t)node * HC + c] = acc;
}

// ---- a_src/a_dst: one thread per (node, head) ----
__global__ void k_att(const float* __restrict__ xw,
                      const float* __restrict__ att_src,
                      const float* __restrict__ att_dst,
                      float* __restrict__ a_src, float* __restrict__ a_dst, int NH) {
    int t = blockIdx.x * 256 + threadIdx.x;
    if (t >= NH) return;
    int n = t >> 3, h = t & 7;
    const float* row = xw + (size_t)n * HC + h * 32;
    const float* as = att_src + h * 32;
    const float* ad = att_dst + h * 32;
    float s1 = 0.f, s2 = 0.f;
    for (int c = 0; c < 32; ++c) {
        s1 = fmaf(row[c], as[c], s1);
        s2 = fmaf(row[c], ad[c], s2);
    }
    a_src[t] = s1;
    a_dst[t] = s2;
}

// ---- init denom & outacc with the self-loop term ----
__global__ void k_init(const float* __restrict__ xw,
                       const float* __restrict__ a_src,
                       const float* __restrict__ a_dst,
                       float* __restrict__ denom, float* __restrict__ outacc, int total) {
    int t = blockIdx.x * 256 + threadIdx.x;   // t = node*256 + ch
    if (t >= total) return;
    int n = t >> 8, ch = t & 255, h = ch >> 5;
    float s = a_src[n * 8 + h] + a_dst[n * 8 + h];
    s = (s > 0.f) ? s : 0.2f * s;
    float p = expf(s);
    outacc[t] = p * xw[t];
    if ((ch & 31) == 0) denom[n * 8 + h] = p;
}

// ---- softmax denominator: thread per (edge, head) ----
__global__ void k_edge_denom(const int* __restrict__ src, const int* __restrict__ dst,
                             const float* __restrict__ a_src, const float* __restrict__ a_dst,
                             float* __restrict__ denom, int EH, int N) {
    int t = blockIdx.x * 256 + threadIdx.x;
    if (t >= EH) return;
    int e = t >> 3, h = t & 7;
    int sj = min(max(src[e], 0), N - 1);
    int di = min(max(dst[e], 0), N - 1);
    float s = a_src[sj * 8 + h] + a_dst[di * 8 + h];
    s = (s > 0.f) ? s : 0.2f * s;
    atomicAdd(&denom[di * 8 + h], expf(s));
}

// ---- aggregation: one block per edge, thread per channel ----
__global__ __launch_bounds__(256) void k_edge_agg(const int* __restrict__ src,
                                                  const int* __restrict__ dst,
                                                  const float* __restrict__ a_src,
                                                  const float* __restrict__ a_dst,
                                                  const float* __restrict__ xw,
                                                  float* __restrict__ outacc, int N) {
    int e = blockIdx.x;
    int ch = threadIdx.x;
    int h = ch >> 5;
    int sj = min(max(src[e], 0), N - 1);
    int di = min(max(dst[e], 0), N - 1);
    float s = a_src[sj * 8 + h] + a_dst[di * 8 + h];
    s = (s > 0.f) ? s : 0.2f * s;
    float p = expf(s);
    atomicAdd(&outacc[(size_t)di * HC + ch], p * xw[(size_t)sj * HC + ch]);
}

// ---- finalize: FLOAT32 output (the round-9 fix) ----
__global__ void k_final(const float* __restrict__ outacc, const float* __restrict__ denom,
                        const float* __restrict__ bias, float* __restrict__ out, int total) {
    int t = blockIdx.x * 256 + threadIdx.x;
    if (t >= total) return;
    int n = t >> 8, ch = t & 255, h = ch >> 5;
    out[t] = outacc[t] / (denom[n * 8 + h] + 1e-16f) + bias[ch];
}

extern "C" void kernel_launch(void* const* d_in, const int* in_sizes, int n_in,
                              void* d_out, int out_size, void* d_ws, size_t ws_size,
                              hipStream_t stream) {
    const float* x       = (const float*)d_in[0];
    const int*   ei      = (const int*)d_in[1];
    const float* W       = (const float*)d_in[2];
    const float* att_src = (const float*)d_in[3];
    const float* att_dst = (const float*)d_in[4];
    const float* bias    = (const float*)d_in[5];
    float*       out     = (float*)d_out;          // fp32 output, per reference dtype

    const int N = in_sizes[0] / IN_C;
    const int E = in_sizes[1] / 2;
    const int* src = ei;        // edge_index row 0  (2,E) int32 row-major
    const int* dst = ei + E;    // edge_index row 1

    char* ws = (char*)d_ws;
    size_t nc = (size_t)N * HC;
    float* xw     = (float*)(ws);
    float* outacc = (float*)(ws + nc * 4);
    float* a_src  = (float*)(ws + nc * 8);
    float* a_dst  = (float*)(ws + nc * 8 + (size_t)N * 32);
    float* denom  = (float*)(ws + nc * 8 + (size_t)N * 64);

    k_gemm<<<N, 256, 0, stream>>>(x, W, xw);
    k_att<<<(N * 8 + 255) / 256, 256, 0, stream>>>(xw, att_src, att_dst, a_src, a_dst, N * 8);
    k_init<<<(N * HC + 255) / 256, 256, 0, stream>>>(xw, a_src, a_dst, denom, outacc, N * HC);
    k_edge_denom<<<(E * 8 + 255) / 256, 256, 0, stream>>>(src, dst, a_src, a_dst, denom, E * 8, N);
    k_edge_agg<<<E, 256, 0, stream>>>(src, dst, a_src, a_dst, xw, outacc, N);
    k_final<<<(out_size + 255) / 256, 256, 0, stream>>>(outacc, denom, bias, out, out_size);
}

// Round 10
// 382.313 us; speedup vs baseline: 2.0548x; 2.0548x over previous
//
#include <hip/hip_runtime.h>
#include <stdint.h>

#define N_NODES 50000
#define HC 256
#define IN_C 128

typedef __bf16 v8bf __attribute__((ext_vector_type(8)));
typedef float  v4f  __attribute__((ext_vector_type(4)));

__device__ __forceinline__ uint16_t f2bf(float f) {
    union { float f; uint32_t i; } c; c.f = f;
    uint32_t x = c.i;
    uint32_t r = x + 0x7fffu + ((x >> 16) & 1u);
    return (uint16_t)(r >> 16);
}
__device__ __forceinline__ void ld4bf(const uint16_t* p, float& f0, float& f1, float& f2, float& f3) {
    uint2 u = *(const uint2*)p;
    union { uint32_t i; float f; } c;
    c.i = u.x << 16;          f0 = c.f;
    c.i = u.x & 0xffff0000u;  f1 = c.f;
    c.i = u.y << 16;          f2 = c.f;
    c.i = u.y & 0xffff0000u;  f3 = c.f;
}

// ---- W fp32 [128][256] -> Wt bf16 [256][128] ----
__global__ void k_wt(const float* __restrict__ W, uint16_t* __restrict__ Wt) {
    int idx = blockIdx.x * 256 + threadIdx.x;   // idx = k*256 + c
    int k = idx >> 8;
    int c = idx & 255;
    Wt[c * IN_C + k] = f2bf(W[idx]);
}

// ---- xw = x @ W via MFMA 16x16x32 bf16; one wave = 16 nodes x 16 cols ----
// writes xw fp32 (for exact logits/self) and xwh bf16 (gather payload)
__global__ __launch_bounds__(256) void k_gemm(const float* __restrict__ x,
                                              const uint16_t* __restrict__ Wt,
                                              float* __restrict__ xw,
                                              uint16_t* __restrict__ xwh) {
    int wid  = blockIdx.x * 4 + (threadIdx.x >> 6);   // 0..49999
    int lane = threadIdx.x & 63;
    int nt = wid >> 4;          // node tile
    int ct = wid & 15;          // col tile
    int node = nt * 16 + (lane & 15);
    int col  = ct * 16 + (lane & 15);
    int kq = (lane >> 4) * 8;
    const float*    xrow = x  + (size_t)node * IN_C + kq;
    const uint16_t* wrow = Wt + (size_t)col  * IN_C + kq;
    v4f acc = {0.f, 0.f, 0.f, 0.f};
#pragma unroll
    for (int s = 0; s < 4; ++s) {
        float4 p0 = *(const float4*)(xrow + s * 32);
        float4 p1 = *(const float4*)(xrow + s * 32 + 4);
        v8bf a;
        a[0] = (__bf16)p0.x; a[1] = (__bf16)p0.y; a[2] = (__bf16)p0.z; a[3] = (__bf16)p0.w;
        a[4] = (__bf16)p1.x; a[5] = (__bf16)p1.y; a[6] = (__bf16)p1.z; a[7] = (__bf16)p1.w;
        v8bf b = *(const v8bf*)(wrow + s * 32);
        acc = __builtin_amdgcn_mfma_f32_16x16x32_bf16(a, b, acc, 0, 0, 0);
    }
    int row0 = (lane >> 4) * 4;
    size_t base = (size_t)(nt * 16 + row0) * HC + ct * 16 + (lane & 15);
#pragma unroll
    for (int r = 0; r < 4; ++r) {
        xw[base + (size_t)r * HC]  = acc[r];
        xwh[base + (size_t)r * HC] = f2bf(acc[r]);
    }
}

// ---- a_src/a_dst [N,8]; one wave per node (reads fp32 xw) ----
__global__ __launch_bounds__(256) void k_att(const float* __restrict__ xw,
                                             const float* __restrict__ att_src,
                                             const float* __restrict__ att_dst,
                                             float* __restrict__ a_src, float* __restrict__ a_dst) {
    int wid  = blockIdx.x * 4 + (threadIdx.x >> 6);
    int lane = threadIdx.x & 63;
    if (wid >= N_NODES) return;
    float4 v  = *(const float4*)(xw + (size_t)wid * HC + lane * 4);
    float4 as = *(const float4*)(att_src + lane * 4);
    float4 ad = *(const float4*)(att_dst + lane * 4);
    float s1 = v.x * as.x + v.y * as.y + v.z * as.z + v.w * as.w;
    float s2 = v.x * ad.x + v.y * ad.y + v.z * ad.z + v.w * ad.w;
#pragma unroll
    for (int m = 1; m < 8; m <<= 1) {
        s1 += __shfl_xor(s1, m, 64);
        s2 += __shfl_xor(s2, m, 64);
    }
    if ((lane & 7) == 0) {
        a_src[wid * 8 + (lane >> 3)] = s1;
        a_dst[wid * 8 + (lane >> 3)] = s2;
    }
}

// ---- CSR build ----
__global__ void k_hist(const int* __restrict__ dst, int* __restrict__ deg, int E) {
    int e = blockIdx.x * 256 + threadIdx.x;
    if (e < E) atomicAdd(&deg[dst[e]], 1);
}

__global__ __launch_bounds__(1024) void k_scan(const int* __restrict__ deg,
                                               int* __restrict__ off, int* __restrict__ cur) {
    __shared__ int sm[1024];
    int tid = threadIdx.x;
    const int CH = (N_NODES + 1023) >> 10;
    int lo = tid * CH;
    int hi = min(lo + CH, N_NODES);
    int sum = 0;
    for (int i = lo; i < hi; ++i) sum += deg[i];
    sm[tid] = sum;
    __syncthreads();
    for (int o = 1; o < 1024; o <<= 1) {
        int v = (tid >= o) ? sm[tid - o] : 0;
        __syncthreads();
        sm[tid] += v;
        __syncthreads();
    }
    int run = (tid == 0) ? 0 : sm[tid - 1];
    for (int i = lo; i < hi; ++i) {
        off[i] = run; cur[i] = run;
        run += deg[i];
    }
    if (tid == 1023) off[N_NODES] = sm[1023];
}

__global__ void k_scatter(const int* __restrict__ src, const int* __restrict__ dst,
                          int* __restrict__ cur, int* __restrict__ csr, int E) {
    int e = blockIdx.x * 256 + threadIdx.x;
    if (e < E) {
        int pos = atomicAdd(&cur[dst[e]], 1);
        csr[pos] = src[e];
    }
}

// ---- aggregation: one wave per destination, plain-exp softmax, no atomics ----
__global__ __launch_bounds__(256) void k_agg(const float* __restrict__ xw,
                                             const uint16_t* __restrict__ xwh,
                                             const float* __restrict__ a_src,
                                             const float* __restrict__ a_dst,
                                             const int* __restrict__ off,
                                             const int* __restrict__ csr,
                                             const float* __restrict__ bias,
                                             float* __restrict__ out) {
    int i    = blockIdx.x * 4 + (threadIdx.x >> 6);
    int lane = threadIdx.x & 63;
    if (i >= N_NODES) return;
    int h = lane >> 3;                 // 8 lanes per head
    float sdst = a_dst[i * 8 + h];

    // self loop
    float s0 = a_src[i * 8 + h] + sdst;
    s0 = (s0 > 0.f) ? s0 : 0.2f * s0;
    float p0 = __expf(s0);
    float l = p0;
    float4 self = *(const float4*)(xw + (size_t)i * HC + lane * 4);
    float a0 = p0 * self.x, a1 = p0 * self.y, a2 = p0 * self.z, a3 = p0 * self.w;

    int start = off[i], end = off[i + 1];
    for (int base = start; base < end; base += 64) {
        int nb = min(64, end - base);
        int myj = (base + lane < end) ? csr[base + lane] : 0;
        for (int t = 0; t < nb; ++t) {
            int j = __shfl(myj, t, 64);
            float s = a_src[j * 8 + h] + sdst;
            s = (s > 0.f) ? s : 0.2f * s;
            float p = __expf(s);
            l += p;
            float f0, f1, f2, f3;
            ld4bf(xwh + (size_t)j * HC + lane * 4, f0, f1, f2, f3);
            a0 = fmaf(p, f0, a0);
            a1 = fmaf(p, f1, a1);
            a2 = fmaf(p, f2, a2);
            a3 = fmaf(p, f3, a3);
        }
    }
    float inv = 1.f / (l + 1e-16f);
    float4 b = *(const float4*)(bias + lane * 4);
    float4 o;
    o.x = fmaf(a0, inv, b.x);
    o.y = fmaf(a1, inv, b.y);
    o.z = fmaf(a2, inv, b.z);
    o.w = fmaf(a3, inv, b.w);
    *(float4*)(out + (size_t)i * HC + lane * 4) = o;
}

extern "C" void kernel_launch(void* const* d_in, const int* in_sizes, int n_in,
                              void* d_out, int out_size, void* d_ws, size_t ws_size,
                              hipStream_t stream) {
    const float* x       = (const float*)d_in[0];
    const int*   ei      = (const int*)d_in[1];
    const float* W       = (const float*)d_in[2];
    const float* att_src = (const float*)d_in[3];
    const float* att_dst = (const float*)d_in[4];
    const float* bias    = (const float*)d_in[5];
    float*       out     = (float*)d_out;

    const int E = in_sizes[1] / 2;
    const int* src = ei;        // (2,E) int32 row-major — verified r9
    const int* dst = ei + E;

    char* ws = (char*)d_ws;
    float*    xw    = (float*)   (ws);                         // 51,200,000 B
    uint16_t* xwh   = (uint16_t*)(ws + 51200000);              // 25,600,000 B
    uint16_t* Wt    = (uint16_t*)(ws + 76800000);              //     65,536 B
    float*    a_src = (float*)   (ws + 76865536);              //  1,600,000 B
    float*    a_dst = (float*)   (ws + 78465536);              //  1,600,000 B
    int*      off   = (int*)     (ws + 80065536);              //    200,004 B
    int*      deg   = (int*)     (ws + 80265540);              //    200,000 B
    int*      cur   = (int*)     (ws + 80465540);              //    200,000 B
    int*      csr   = (int*)     (ws + 80665540);              //  2,000,000 B

    k_wt<<<128, 256, 0, stream>>>(W, Wt);
    k_gemm<<<12500, 256, 0, stream>>>(x, Wt, xw, xwh);
    k_att<<<12500, 256, 0, stream>>>(xw, att_src, att_dst, a_src, a_dst);
    hipMemsetAsync(deg, 0, N_NODES * sizeof(int), stream);
    k_hist<<<(E + 255) / 256, 256, 0, stream>>>(dst, deg, E);
    k_scan<<<1, 1024, 0, stream>>>(deg, off, cur);
    k_scatter<<<(E + 255) / 256, 256, 0, stream>>>(src, dst, cur, csr, E);
    k_agg<<<12500, 256, 0, stream>>>(xw, xwh, a_src, a_dst, off, csr, bias, out);
}

// Round 11
// 276.713 us; speedup vs baseline: 2.8389x; 1.3816x over previous
//
#include <hip/hip_runtime.h>
#include <stdint.h>

#define N_NODES 50000
#define HC 256
#define IN_C 128
#define SCAN_B 196          // ceil(50000/256)

typedef __bf16 v8bf __attribute__((ext_vector_type(8)));
typedef float  v4f  __attribute__((ext_vector_type(4)));

__device__ __forceinline__ uint16_t f2bf(float f) {
    union { float f; uint32_t i; } c; c.f = f;
    uint32_t x = c.i;
    uint32_t r = x + 0x7fffu + ((x >> 16) & 1u);
    return (uint16_t)(r >> 16);
}
__device__ __forceinline__ void ld4bf(uint2 u, float& f0, float& f1, float& f2, float& f3) {
    union { uint32_t i; float f; } c;
    c.i = u.x << 16;          f0 = c.f;
    c.i = u.x & 0xffff0000u;  f1 = c.f;
    c.i = u.y << 16;          f2 = c.f;
    c.i = u.y & 0xffff0000u;  f3 = c.f;
}

// ---- W fp32 [128][256] -> Wt bf16 [256][128] ----
__global__ void k_wt(const float* __restrict__ W, uint16_t* __restrict__ Wt) {
    int idx = blockIdx.x * 256 + threadIdx.x;
    int k = idx >> 8;
    int c = idx & 255;
    Wt[c * IN_C + k] = f2bf(W[idx]);
}

// ---- xw = x @ W via MFMA; writes fp32 (logits/self) + bf16 (gather payload) ----
__global__ __launch_bounds__(256) void k_gemm(const float* __restrict__ x,
                                              const uint16_t* __restrict__ Wt,
                                              float* __restrict__ xw,
                                              uint16_t* __restrict__ xwh) {
    int wid  = blockIdx.x * 4 + (threadIdx.x >> 6);
    int lane = threadIdx.x & 63;
    int nt = wid >> 4;
    int ct = wid & 15;
    int node = nt * 16 + (lane & 15);
    int col  = ct * 16 + (lane & 15);
    int kq = (lane >> 4) * 8;
    const float*    xrow = x  + (size_t)node * IN_C + kq;
    const uint16_t* wrow = Wt + (size_t)col  * IN_C + kq;
    v4f acc = {0.f, 0.f, 0.f, 0.f};
#pragma unroll
    for (int s = 0; s < 4; ++s) {
        float4 p0 = *(const float4*)(xrow + s * 32);
        float4 p1 = *(const float4*)(xrow + s * 32 + 4);
        v8bf a;
        a[0] = (__bf16)p0.x; a[1] = (__bf16)p0.y; a[2] = (__bf16)p0.z; a[3] = (__bf16)p0.w;
        a[4] = (__bf16)p1.x; a[5] = (__bf16)p1.y; a[6] = (__bf16)p1.z; a[7] = (__bf16)p1.w;
        v8bf b = *(const v8bf*)(wrow + s * 32);
        acc = __builtin_amdgcn_mfma_f32_16x16x32_bf16(a, b, acc, 0, 0, 0);
    }
    int row0 = (lane >> 4) * 4;
    size_t base = (size_t)(nt * 16 + row0) * HC + ct * 16 + (lane & 15);
#pragma unroll
    for (int r = 0; r < 4; ++r) {
        xw[base + (size_t)r * HC]  = acc[r];
        xwh[base + (size_t)r * HC] = f2bf(acc[r]);
    }
}

// ---- a_src/a_dst [N,8]; one wave per node ----
__global__ __launch_bounds__(256) void k_att(const float* __restrict__ xw,
                                             const float* __restrict__ att_src,
                                             const float* __restrict__ att_dst,
                                             float* __restrict__ a_src, float* __restrict__ a_dst) {
    int wid  = blockIdx.x * 4 + (threadIdx.x >> 6);
    int lane = threadIdx.x & 63;
    if (wid >= N_NODES) return;
    float4 v  = *(const float4*)(xw + (size_t)wid * HC + lane * 4);
    float4 as = *(const float4*)(att_src + lane * 4);
    float4 ad = *(const float4*)(att_dst + lane * 4);
    float s1 = v.x * as.x + v.y * as.y + v.z * as.z + v.w * as.w;
    float s2 = v.x * ad.x + v.y * ad.y + v.z * ad.z + v.w * ad.w;
#pragma unroll
    for (int m = 1; m < 8; m <<= 1) {
        s1 += __shfl_xor(s1, m, 64);
        s2 += __shfl_xor(s2, m, 64);
    }
    if ((lane & 7) == 0) {
        a_src[wid * 8 + (lane >> 3)] = s1;
        a_dst[wid * 8 + (lane >> 3)] = s2;
    }
}

// ---- CSR build: hist + 3-kernel parallel scan + scatter ----
__global__ void k_hist(const int* __restrict__ dst, int* __restrict__ deg, int E) {
    int e = blockIdx.x * 256 + threadIdx.x;
    if (e < E) atomicAdd(&deg[dst[e]], 1);
}

__global__ __launch_bounds__(256) void k_scan1(const int* __restrict__ deg, int* __restrict__ bsum) {
    __shared__ int sm[256];
    int tid = threadIdx.x;
    int i = blockIdx.x * 256 + tid;
    int v = (i < N_NODES) ? deg[i] : 0;
    sm[tid] = v;
    __syncthreads();
#pragma unroll
    for (int o = 128; o > 0; o >>= 1) {
        if (tid < o) sm[tid] += sm[tid + o];
        __syncthreads();
    }
    if (tid == 0) bsum[blockIdx.x] = sm[0];
}

__global__ __launch_bounds__(256) void k_scan2(int* __restrict__ bsum, int* __restrict__ off) {
    __shared__ int sm[256];
    int tid = threadIdx.x;
    int v = (tid < SCAN_B) ? bsum[tid] : 0;
    sm[tid] = v;
    __syncthreads();
#pragma unroll
    for (int o = 1; o < 256; o <<= 1) {
        int t = (tid >= o) ? sm[tid - o] : 0;
        __syncthreads();
        sm[tid] += t;
        __syncthreads();
    }
    bsum[tid] = sm[tid] - v;                 // exclusive
    if (tid == 255) off[N_NODES] = sm[255];  // total
}

__global__ __launch_bounds__(256) void k_scan3(const int* __restrict__ deg,
                                               const int* __restrict__ bsum,
                                               int* __restrict__ off, int* __restrict__ cur) {
    __shared__ int sm[256];
    int tid = threadIdx.x;
    int i = blockIdx.x * 256 + tid;
    int v = (i < N_NODES) ? deg[i] : 0;
    sm[tid] = v;
    __syncthreads();
#pragma unroll
    for (int o = 1; o < 256; o <<= 1) {
        int t = (tid >= o) ? sm[tid - o] : 0;
        __syncthreads();
        sm[tid] += t;
        __syncthreads();
    }
    if (i < N_NODES) {
        int excl = sm[tid] - v + bsum[blockIdx.x];
        off[i] = excl;
        cur[i] = excl;
    }
}

__global__ void k_scatter(const int* __restrict__ src, const int* __restrict__ dst,
                          int* __restrict__ cur, int* __restrict__ csr, int E) {
    int e = blockIdx.x * 256 + threadIdx.x;
    if (e < E) {
        int pos = atomicAdd(&cur[dst[e]], 1);
        csr[pos] = src[e];
    }
}

// ---- aggregation: one wave per destination, unroll-by-2 for MLP ----
__global__ __launch_bounds__(256) void k_agg(const float* __restrict__ xw,
                                             const uint16_t* __restrict__ xwh,
                                             const float* __restrict__ a_src,
                                             const float* __restrict__ a_dst,
                                             const int* __restrict__ off,
                                             const int* __restrict__ csr,
                                             const float* __restrict__ bias,
                                             float* __restrict__ out) {
    int i    = blockIdx.x * 4 + (threadIdx.x >> 6);
    int lane = threadIdx.x & 63;
    if (i >= N_NODES) return;
    int h = lane >> 3;
    float sdst = a_dst[i * 8 + h];

    float s0 = a_src[i * 8 + h] + sdst;
    s0 = (s0 > 0.f) ? s0 : 0.2f * s0;
    float p0 = __expf(s0);
    float l = p0;
    float4 self = *(const float4*)(xw + (size_t)i * HC + lane * 4);
    float a0 = p0 * self.x, a1 = p0 * self.y, a2 = p0 * self.z, a3 = p0 * self.w;

    int start = off[i], end = off[i + 1];
    for (int base = start; base < end; base += 64) {
        int nb = min(64, end - base);
        int myj = (base + lane < end) ? csr[base + lane] : 0;
        int t = 0;
        for (; t + 1 < nb; t += 2) {
            int j0 = __shfl(myj, t, 64);
            int j1 = __shfl(myj, t + 1, 64);
            float sa0 = a_src[j0 * 8 + h];
            float sa1 = a_src[j1 * 8 + h];
            uint2 u0 = *(const uint2*)(xwh + (size_t)j0 * HC + lane * 4);
            uint2 u1 = *(const uint2*)(xwh + (size_t)j1 * HC + lane * 4);
            float sA = sa0 + sdst; sA = (sA > 0.f) ? sA : 0.2f * sA;
            float sB = sa1 + sdst; sB = (sB > 0.f) ? sB : 0.2f * sB;
            float pA = __expf(sA);
            float pB = __expf(sB);
            l += pA + pB;
            float f0, f1, f2, f3, g0, g1, g2, g3;
            ld4bf(u0, f0, f1, f2, f3);
            ld4bf(u1, g0, g1, g2, g3);
            a0 = fmaf(pA, f0, a0); a1 = fmaf(pA, f1, a1);
            a2 = fmaf(pA, f2, a2); a3 = fmaf(pA, f3, a3);
            a0 = fmaf(pB, g0, a0); a1 = fmaf(pB, g1, a1);
            a2 = fmaf(pB, g2, a2); a3 = fmaf(pB, g3, a3);
        }
        if (t < nb) {
            int j = __shfl(myj, t, 64);
            float s = a_src[j * 8 + h] + sdst;
            s = (s > 0.f) ? s : 0.2f * s;
            float p = __expf(s);
            l += p;
            uint2 u = *(const uint2*)(xwh + (size_t)j * HC + lane * 4);
            float f0, f1, f2, f3;
            ld4bf(u, f0, f1, f2, f3);
            a0 = fmaf(p, f0, a0); a1 = fmaf(p, f1, a1);
            a2 = fmaf(p, f2, a2); a3 = fmaf(p, f3, a3);
        }
    }
    float inv = 1.f / (l + 1e-16f);
    float4 b = *(const float4*)(bias + lane * 4);
    float4 o;
    o.x = fmaf(a0, inv, b.x);
    o.y = fmaf(a1, inv, b.y);
    o.z = fmaf(a2, inv, b.z);
    o.w = fmaf(a3, inv, b.w);
    *(float4*)(out + (size_t)i * HC + lane * 4) = o;
}

extern "C" void kernel_launch(void* const* d_in, const int* in_sizes, int n_in,
                              void* d_out, int out_size, void* d_ws, size_t ws_size,
                              hipStream_t stream) {
    const float* x       = (const float*)d_in[0];
    const int*   ei      = (const int*)d_in[1];
    const float* W       = (const float*)d_in[2];
    const float* att_src = (const float*)d_in[3];
    const float* att_dst = (const float*)d_in[4];
    const float* bias    = (const float*)d_in[5];
    float*       out     = (float*)d_out;

    const int E = in_sizes[1] / 2;
    const int* src = ei;        // (2,E) int32 row-major — verified r9
    const int* dst = ei + E;

    char* ws = (char*)d_ws;
    float*    xw    = (float*)   (ws);                         // 51,200,000 B
    uint16_t* xwh   = (uint16_t*)(ws + 51200000);              // 25,600,000 B
    uint16_t* Wt    = (uint16_t*)(ws + 76800000);              //     65,536 B
    float*    a_src = (float*)   (ws + 76865536);              //  1,600,000 B
    float*    a_dst = (float*)   (ws + 78465536);              //  1,600,000 B
    int*      off   = (int*)     (ws + 80065536);              //    200,004 B
    int*      deg   = (int*)     (ws + 80265540);              //    200,000 B
    int*      cur   = (int*)     (ws + 80465540);              //    200,000 B
    int*      csr   = (int*)     (ws + 80665540);              //  2,000,000 B
    int*      bsum  = (int*)     (ws + 82665540);              //      1,024 B

    k_wt<<<128, 256, 0, stream>>>(W, Wt);
    k_gemm<<<12500, 256, 0, stream>>>(x, Wt, xw, xwh);
    k_att<<<12500, 256, 0, stream>>>(xw, att_src, att_dst, a_src, a_dst);
    hipMemsetAsync(deg, 0, N_NODES * sizeof(int), stream);
    k_hist<<<(E + 255) / 256, 256, 0, stream>>>(dst, deg, E);
    k_scan1<<<SCAN_B, 256, 0, stream>>>(deg, bsum);
    k_scan2<<<1, 256, 0, stream>>>(bsum, off);
    k_scan3<<<SCAN_B, 256, 0, stream>>>(deg, bsum, off, cur);
    k_scatter<<<(E + 255) / 256, 256, 0, stream>>>(src, dst, cur, csr, E);
    k_agg<<<12500, 256, 0, stream>>>(xw, xwh, a_src, a_dst, off, csr, bias, out);
}